// Round 1
// baseline (156.397 us; speedup 1.0000x reference)
//
#include <hip/hip_runtime.h>

#define NPTS 131072
#define NB   1024
#define NI   256
#define NA   32
#define RR   8
#define ND   28

__device__ __forceinline__ float shflf(float v, int src) {
  return __shfl(v, src, 64);
}

// atoms[a][vox][d] (28) -> atomsT[vox][a][d-padded-to-32]
__global__ __launch_bounds__(256) void transpose_atoms(const float* __restrict__ atoms,
                                                       float* __restrict__ atomsT) {
  int idx = blockIdx.x * 256 + threadIdx.x;   // < 512*1024
  int vox = idx >> 10;
  int rest = idx & 1023;
  int a = rest >> 5;
  int d = rest & 31;
  float v = 0.f;
  if (d < ND) v = atoms[(a * 512 + vox) * ND + d];
  atomsT[idx] = v;
}

// one wave per point
__global__ __launch_bounds__(256) void point_kernel(
    const float* __restrict__ queries, const float* __restrict__ intrs_pts,
    const float* __restrict__ rays_d, const int* __restrict__ scatter_idx,
    const float* __restrict__ atomsT,
    float* __restrict__ sigma_d, float* __restrict__ rgb_d) {
  int p = blockIdx.x * 4 + (threadIdx.x >> 6);
  int lane = threadIdx.x & 63;

  float cx = fminf(fmaxf(intrs_pts[p * 3 + 0] * 7.f, 0.f), 7.f);
  float cy = fminf(fmaxf(intrs_pts[p * 3 + 1] * 7.f, 0.f), 7.f);
  float cz = fminf(fmaxf(intrs_pts[p * 3 + 2] * 7.f, 0.f), 7.f);
  int ix = (int)floorf(cx); ix = ix > 6 ? 6 : ix;
  int iy = (int)floorf(cy); iy = iy > 6 ? 6 : iy;
  int iz = (int)floorf(cz); iz = iz > 6 ? 6 : iz;
  float fx = cx - (float)ix;
  float fy = cy - (float)iy;
  float fz = cz - (float)iz;

  float qv = queries[p * NA + (lane & 31)];
  int h = lane >> 5;       // even/odd half of the a-sum
  int dd = lane & 31;      // output channel
  float qa[16];
#pragma unroll
  for (int k = 0; k < 16; k++) qa[k] = shflf(qv, h + 2 * k);

  float acc = 0.f;
#pragma unroll
  for (int c = 0; c < 8; c++) {
    int dx = c >> 2, dy = (c >> 1) & 1, dz = c & 1;
    int vox = ((ix + dx) * RR + (iy + dy)) * RR + (iz + dz);
    float w = (dx ? fx : 1.f - fx) * (dy ? fy : 1.f - fy) * (dz ? fz : 1.f - fz);
    const float* bp = atomsT + vox * 1024 + (h << 5) + dd;
    float s0 = 0.f, s1 = 0.f, s2 = 0.f, s3 = 0.f;
#pragma unroll
    for (int k = 0; k < 16; k += 4) {
      s0 += qa[k + 0] * bp[(k + 0) * 64];
      s1 += qa[k + 1] * bp[(k + 1) * 64];
      s2 += qa[k + 2] * bp[(k + 2) * 64];
      s3 += qa[k + 3] * bp[(k + 3) * 64];
    }
    acc += w * ((s0 + s1) + (s2 + s3));
  }
  acc += __shfl_xor(acc, 32, 64);  // combine even/odd a halves; lanes now hold data[dd]

  int sidx = scatter_idx[p];
  int b = sidx >> 8;  // NI = 256

  float rxv = rays_d[b * 3 + 0], ryv = rays_d[b * 3 + 1], rzv = rays_d[b * 3 + 2];
  float inv = rsqrtf(rxv * rxv + ryv * ryv + rzv * rzv);
  float X = rxv * inv, Y = ryv * inv, Z = rzv * inv;
  float shb[9];
  shb[0] = 0.28209479177387814f;
  shb[1] = -0.4886025119029199f * Y;
  shb[2] = 0.4886025119029199f * Z;
  shb[3] = -0.4886025119029199f * X;
  shb[4] = 1.0925484305920792f * X * Y;
  shb[5] = -1.0925484305920792f * Y * Z;
  shb[6] = 0.31539156525252005f * (2.f * Z * Z - X * X - Y * Y);
  shb[7] = -1.0925484305920792f * X * Z;
  shb[8] = 0.5462742152960396f * (X * X - Y * Y);

  // rgb_m[c] = sum_sh shb[sh] * data[c*9+sh], computed with c = lane (valid for lane<3)
  float rgbc = 0.f;
#pragma unroll
  for (int sh = 0; sh < 9; sh++) {
    rgbc += shb[sh] * shflf(acc, (lane * 9 + sh) & 63);
  }
  if (lane < 3) rgb_d[(size_t)sidx * 3 + lane] = rgbc;
  if (lane == 27) sigma_d[sidx] = acc;  // data[27]
}

// one 256-thread block per ray
__global__ __launch_bounds__(256) void ray_kernel(
    const float* __restrict__ intersections, const float* __restrict__ rays_d,
    const float* __restrict__ sigma_d, const float* __restrict__ rgb_d,
    float* __restrict__ out) {
  int b = blockIdx.x;
  int i = threadIdx.x;

  float t0 = intersections[b * (NI + 1) + i];
  float t1 = intersections[b * (NI + 1) + i + 1];
  float rxv = rays_d[b * 3 + 0], ryv = rays_d[b * 3 + 1], rzv = rays_d[b * 3 + 2];
  float nrm = sqrtf(rxv * rxv + ryv * ryv + rzv * rzv);
  float dist = (t1 - t0) * nrm;
  float mid = 0.5f * (t0 + t1);

  float sg = fmaxf(sigma_d[b * NI + i], 0.f);
  float alpha = 1.f - expf(-sg * dist);
  out[3072 + b * NI + i] = alpha;

  float x = 1.f - alpha + 1e-10f;

  __shared__ float s[NI];
  s[i] = x;
  __syncthreads();
#pragma unroll
  for (int off = 1; off < NI; off <<= 1) {
    float v = s[i];
    float pv = (i >= off) ? s[i - off] : 1.f;
    __syncthreads();
    s[i] = v * pv;
    __syncthreads();
  }
  float trans = (i == 0) ? 1.f : s[i - 1];
  float al = alpha * trans;

  float r0 = rgb_d[(size_t)(b * NI + i) * 3 + 0];
  float r1 = rgb_d[(size_t)(b * NI + i) * 3 + 1];
  float r2 = rgb_d[(size_t)(b * NI + i) * 3 + 2];
  float g0 = 1.f / (1.f + expf(-r0));
  float g1 = 1.f / (1.f + expf(-r1));
  float g2 = 1.f / (1.f + expf(-r2));

  float v0 = al;            // acc
  float v1 = al * mid;      // depth
  float v2 = al * g0;
  float v3 = al * g1;
  float v4 = al * g2;
#pragma unroll
  for (int off = 1; off < 64; off <<= 1) {
    v0 += __shfl_xor(v0, off, 64);
    v1 += __shfl_xor(v1, off, 64);
    v2 += __shfl_xor(v2, off, 64);
    v3 += __shfl_xor(v3, off, 64);
    v4 += __shfl_xor(v4, off, 64);
  }
  __shared__ float wred[4][5];
  int wid = i >> 6;
  int lane = i & 63;
  if (lane == 0) {
    wred[wid][0] = v0; wred[wid][1] = v1; wred[wid][2] = v2;
    wred[wid][3] = v3; wred[wid][4] = v4;
  }
  __syncthreads();
  if (i == 0) {
    float a0 = 0.f, a1 = 0.f, a2 = 0.f, a3 = 0.f, a4 = 0.f;
#pragma unroll
    for (int w = 0; w < 4; w++) {
      a0 += wred[w][0]; a1 += wred[w][1]; a2 += wred[w][2];
      a3 += wred[w][3]; a4 += wred[w][4];
    }
    float white = 1.f - a0;
    out[b * 3 + 0] = a2 + white;
    out[b * 3 + 1] = a3 + white;
    out[b * 3 + 2] = a4 + white;
    out[3072 + NB * NI + b] = a1;  // depth at offset 265216
  }
}

extern "C" void kernel_launch(void* const* d_in, const int* in_sizes, int n_in,
                              void* d_out, int out_size, void* d_ws, size_t ws_size,
                              hipStream_t stream) {
  const float* rays_d        = (const float*)d_in[0];
  const float* queries       = (const float*)d_in[1];
  const float* intrs_pts     = (const float*)d_in[2];
  const float* intersections = (const float*)d_in[3];
  const float* atoms         = (const float*)d_in[4];
  const int*   scatter_idx   = (const int*)d_in[5];
  float* out = (float*)d_out;

  float* sigma_d = (float*)d_ws;                 // NB*NI floats      (1 MB)
  float* rgb_d   = sigma_d + NB * NI;            // NB*NI*3 floats    (3 MB)
  float* atomsT  = rgb_d + (size_t)NB * NI * 3;  // 512*1024 floats   (2 MB)

  // zero the scatter targets (empty slots must be exactly 0)
  hipMemsetAsync(d_ws, 0, sizeof(float) * (size_t)NB * NI * 4, stream);

  transpose_atoms<<<(512 * 1024) / 256, 256, 0, stream>>>(atoms, atomsT);
  point_kernel<<<NPTS / 4, 256, 0, stream>>>(queries, intrs_pts, rays_d,
                                             scatter_idx, atomsT, sigma_d, rgb_d);
  ray_kernel<<<NB, 256, 0, stream>>>(intersections, rays_d, sigma_d, rgb_d, out);
}

// Round 3
// 97.146 us; speedup vs baseline: 1.6099x; 1.6099x over previous
//
#include <hip/hip_runtime.h>

#define NPTS 131072
#define NB   1024
#define NI   256
#define NA   32
#define RR   8
#define ND   28

typedef _Float16 half2v __attribute__((ext_vector_type(2)));

__device__ __forceinline__ float shflf(float v, int src) {
  return __shfl(v, src, 64);
}

// atoms[a][vox][d] (f32, d=28) -> atomsT2[vox][a2][d] (half2 over a-pairs, d padded to 32)
// element (vox, a2, d) = half2( atoms[2*a2][vox][d], atoms[2*a2+1][vox][d] )
__global__ __launch_bounds__(256) void transpose_atoms(const float* __restrict__ atoms,
                                                       half2v* __restrict__ atomsT2) {
  int idx = blockIdx.x * 256 + threadIdx.x;   // < 512*512
  int vox = idx >> 9;
  int r = idx & 511;
  int a2 = r >> 5;
  int d = r & 31;
  float lo = 0.f, hi = 0.f;
  if (d < ND) {
    lo = atoms[((2 * a2) * 512 + vox) * ND + d];
    hi = atoms[((2 * a2 + 1) * 512 + vox) * ND + d];
  }
  half2v v;
  v.x = (_Float16)lo;  // rte
  v.y = (_Float16)hi;
  atomsT2[idx] = v;
}

// one wave per point; lane = h*32 + d  (h = a-half, d = output channel)
__global__ __launch_bounds__(256) void point_kernel(
    const float* __restrict__ queries, const float* __restrict__ intrs_pts,
    const float* __restrict__ rays_d, const int* __restrict__ scatter_idx,
    const half2v* __restrict__ atomsT2,
    float* __restrict__ sigma_d, float* __restrict__ rgb_d) {
  int p = blockIdx.x * 4 + (threadIdx.x >> 6);
  int lane = threadIdx.x & 63;
  int d = lane & 31;
  int h = lane >> 5;

  float cx = fminf(fmaxf(intrs_pts[p * 3 + 0] * 7.f, 0.f), 7.f);
  float cy = fminf(fmaxf(intrs_pts[p * 3 + 1] * 7.f, 0.f), 7.f);
  float cz = fminf(fmaxf(intrs_pts[p * 3 + 2] * 7.f, 0.f), 7.f);
  int ix = (int)floorf(cx); ix = ix > 6 ? 6 : ix;
  int iy = (int)floorf(cy); iy = iy > 6 ? 6 : iy;
  int iz = (int)floorf(cz); iz = iz > 6 ? 6 : iz;
  float fx = cx - (float)ix;
  float fy = cy - (float)iy;
  float fz = cz - (float)iz;

  // q2[k] = half2(q[16h+2k], q[16h+2k+1])  -> pairs along the a-axis for this half
  float qv = queries[p * NA + d];
  half2v q2[8];
#pragma unroll
  for (int k = 0; k < 8; k++) {
    float qlo = shflf(qv, 16 * h + 2 * k);
    float qhi = shflf(qv, 16 * h + 2 * k + 1);
    half2v t;
    t.x = (_Float16)qlo;
    t.y = (_Float16)qhi;
    q2[k] = t;
  }

  float acc = 0.f;
#pragma unroll
  for (int c = 0; c < 8; c++) {
    int dx = c >> 2, dy = (c >> 1) & 1, dz = c & 1;
    int vox = ((ix + dx) * RR + (iy + dy)) * RR + (iz + dz);
    float w = (dx ? fx : 1.f - fx) * (dy ? fy : 1.f - fy) * (dz ? fz : 1.f - fz);
    // layout: atomsT2[vox*512 + a2*32 + d], a2 = h*8 + k
    const half2v* bp = atomsT2 + vox * 512 + (h << 8) + d;
    float cacc = 0.f;
#pragma unroll
    for (int k = 0; k < 8; k++) {
      cacc = __builtin_amdgcn_fdot2(bp[k * 32], q2[k], cacc, false);
    }
    acc += w * cacc;
  }
  acc += __shfl_xor(acc, 32, 64);  // combine a-halves; lanes now hold data[d]

  int sidx = scatter_idx[p];
  int b = sidx >> 8;  // NI = 256

  float rxv = rays_d[b * 3 + 0], ryv = rays_d[b * 3 + 1], rzv = rays_d[b * 3 + 2];
  float inv = rsqrtf(rxv * rxv + ryv * ryv + rzv * rzv);
  float X = rxv * inv, Y = ryv * inv, Z = rzv * inv;
  float shb[9];
  shb[0] = 0.28209479177387814f;
  shb[1] = -0.4886025119029199f * Y;
  shb[2] = 0.4886025119029199f * Z;
  shb[3] = -0.4886025119029199f * X;
  shb[4] = 1.0925484305920792f * X * Y;
  shb[5] = -1.0925484305920792f * Y * Z;
  shb[6] = 0.31539156525252005f * (2.f * Z * Z - X * X - Y * Y);
  shb[7] = -1.0925484305920792f * X * Z;
  shb[8] = 0.5462742152960396f * (X * X - Y * Y);

  // rgb_m[c] = sum_sh shb[sh] * data[c*9+sh], computed with c = lane (valid for lane<3)
  float rgbc = 0.f;
#pragma unroll
  for (int sh = 0; sh < 9; sh++) {
    rgbc += shb[sh] * shflf(acc, (lane * 9 + sh) & 63);
  }
  if (lane < 3) rgb_d[(size_t)sidx * 3 + lane] = rgbc;
  if (lane == 27) sigma_d[sidx] = acc;  // data[27]
}

// one 256-thread block per ray
__global__ __launch_bounds__(256) void ray_kernel(
    const float* __restrict__ intersections, const float* __restrict__ rays_d,
    const float* __restrict__ sigma_d, const float* __restrict__ rgb_d,
    float* __restrict__ out) {
  int b = blockIdx.x;
  int i = threadIdx.x;

  float t0 = intersections[b * (NI + 1) + i];
  float t1 = intersections[b * (NI + 1) + i + 1];
  float rxv = rays_d[b * 3 + 0], ryv = rays_d[b * 3 + 1], rzv = rays_d[b * 3 + 2];
  float nrm = sqrtf(rxv * rxv + ryv * ryv + rzv * rzv);
  float dist = (t1 - t0) * nrm;
  float mid = 0.5f * (t0 + t1);

  float sg = fmaxf(sigma_d[b * NI + i], 0.f);
  float alpha = 1.f - expf(-sg * dist);
  out[3072 + b * NI + i] = alpha;

  float x = 1.f - alpha + 1e-10f;

  __shared__ float s[NI];
  s[i] = x;
  __syncthreads();
#pragma unroll
  for (int off = 1; off < NI; off <<= 1) {
    float v = s[i];
    float pv = (i >= off) ? s[i - off] : 1.f;
    __syncthreads();
    s[i] = v * pv;
    __syncthreads();
  }
  float trans = (i == 0) ? 1.f : s[i - 1];
  float al = alpha * trans;

  float r0 = rgb_d[(size_t)(b * NI + i) * 3 + 0];
  float r1 = rgb_d[(size_t)(b * NI + i) * 3 + 1];
  float r2 = rgb_d[(size_t)(b * NI + i) * 3 + 2];
  float g0 = 1.f / (1.f + expf(-r0));
  float g1 = 1.f / (1.f + expf(-r1));
  float g2 = 1.f / (1.f + expf(-r2));

  float v0 = al;            // acc
  float v1 = al * mid;      // depth
  float v2 = al * g0;
  float v3 = al * g1;
  float v4 = al * g2;
#pragma unroll
  for (int off = 1; off < 64; off <<= 1) {
    v0 += __shfl_xor(v0, off, 64);
    v1 += __shfl_xor(v1, off, 64);
    v2 += __shfl_xor(v2, off, 64);
    v3 += __shfl_xor(v3, off, 64);
    v4 += __shfl_xor(v4, off, 64);
  }
  __shared__ float wred[4][5];
  int wid = i >> 6;
  int lane = i & 63;
  if (lane == 0) {
    wred[wid][0] = v0; wred[wid][1] = v1; wred[wid][2] = v2;
    wred[wid][3] = v3; wred[wid][4] = v4;
  }
  __syncthreads();
  if (i == 0) {
    float a0 = 0.f, a1 = 0.f, a2 = 0.f, a3 = 0.f, a4 = 0.f;
#pragma unroll
    for (int w = 0; w < 4; w++) {
      a0 += wred[w][0]; a1 += wred[w][1]; a2 += wred[w][2];
      a3 += wred[w][3]; a4 += wred[w][4];
    }
    float white = 1.f - a0;
    out[b * 3 + 0] = a2 + white;
    out[b * 3 + 1] = a3 + white;
    out[b * 3 + 2] = a4 + white;
    out[3072 + NB * NI + b] = a1;  // depth at offset 265216
  }
}

extern "C" void kernel_launch(void* const* d_in, const int* in_sizes, int n_in,
                              void* d_out, int out_size, void* d_ws, size_t ws_size,
                              hipStream_t stream) {
  const float* rays_d        = (const float*)d_in[0];
  const float* queries       = (const float*)d_in[1];
  const float* intrs_pts     = (const float*)d_in[2];
  const float* intersections = (const float*)d_in[3];
  const float* atoms         = (const float*)d_in[4];
  const int*   scatter_idx   = (const int*)d_in[5];
  float* out = (float*)d_out;

  float* sigma_d  = (float*)d_ws;                        // NB*NI floats      (1 MB)
  float* rgb_d    = sigma_d + NB * NI;                   // NB*NI*3 floats    (3 MB)
  half2v* atomsT2 = (half2v*)(rgb_d + (size_t)NB * NI * 3);  // 512*512 half2 (1 MB)

  // zero the scatter targets (empty slots must be exactly 0)
  (void)hipMemsetAsync(d_ws, 0, sizeof(float) * (size_t)NB * NI * 4, stream);

  transpose_atoms<<<(512 * 512) / 256, 256, 0, stream>>>(atoms, atomsT2);
  point_kernel<<<NPTS / 4, 256, 0, stream>>>(queries, intrs_pts, rays_d,
                                             scatter_idx, atomsT2, sigma_d, rgb_d);
  ray_kernel<<<NB, 256, 0, stream>>>(intersections, rays_d, sigma_d, rgb_d, out);
}